// Round 11
// baseline (322.647 us; speedup 1.0000x reference)
//
#include <hip/hip_runtime.h>

#define N_NODES_C 50000
#define N_EDGES_C 800000
#define N_EDGES2_C (2 * N_EDGES_C)
#define D 128
#define NSHARD 8
#define OFCAP 4096 // overflow list capacity (expected use ~3 edges)

// Bucketed append: BROWS rows per bucket, per-XCD sub-buckets.
#define BROWS 4
#define NBKT (N_NODES_C / BROWS)   // 12500 (exact)
#define NSB (NSHARD * NBKT)        // 100000 sub-buckets
#define BCAP 32                    // entries per sub-bucket (mean 16, +4 sigma)

#define GNODES 64
#define LDP 132                                            // pad: multiple of 4 floats
#define GGRID ((N_NODES_C + GNODES - 1) / GNODES)          // 782 gemm blocks
#define FGRID 2048                                         // fill blocks
#define FEPB ((N_EDGES2_C + FGRID - 1) / FGRID)            // 782 edges/block
#define TOTG (GGRID + FGRID)                               // 2830

static __device__ __forceinline__ unsigned short f2bf(float f) {
  unsigned u = __float_as_uint(f);
  u += 0x7fff + ((u >> 16) & 1);  // round-to-nearest-even
  return (unsigned short)(u >> 16);
}
static __device__ __forceinline__ float bf_lo(unsigned u) {
  return __uint_as_float(u << 16);
}
static __device__ __forceinline__ float bf_hi(unsigned u) {
  return __uint_as_float(u & 0xffff0000u);
}

// Physical XCD id (0..7), wave-uniform; steers L2 locality of the shards.
static __device__ __forceinline__ int xcd_id() {
  int v;
  asm volatile("s_getreg_b32 %0, hwreg(HW_REG_XCC_ID, 0, 4)" : "=s"(v));
  return v & (NSHARD - 1);
}

// ---------------------------------------------------------------------------
// Kernel 1: zero bcursor[NSB] + ofcnt (adjacent). int4-vectorized, ~3 us.
// (alpha moved to gather's epilogue via the flag-in-LSB deferral — R7-proven
// correctness; R7's regression was alpha-in-GEMM-block placement, not the
// deferral itself.)
// ---------------------------------------------------------------------------
__global__ __launch_bounds__(256) void zero_kernel(int4* __restrict__ p) {
  int g = blockIdx.x * 256 + threadIdx.x;
  if (g < (NSB + 64) / 4) p[g] = make_int4(0, 0, 0, 0);
}

// ---------------------------------------------------------------------------
// Kernel 2 (FUSED, block-specialized): GGRID gemm blocks + FGRID fill blocks,
// Bresenham-interleaved. gemm body unchanged (R6-verified).
// fill: 3 nt-loads -> pack -> atomic -> store. No alpha dependency: the f32
// LSB of the stored value carries the lp(1)/hp(0) flag (2^-23 rel error).
// ---------------------------------------------------------------------------
__global__ __launch_bounds__(256) void gemm_fill_kernel(
    const float* __restrict__ x,
    const float* __restrict__ W,
    unsigned* __restrict__ y,        // [N][64] packed words
    const int* __restrict__ lp_rows, const int* __restrict__ lp_cols,
    const float* __restrict__ lp_vals,
    const int* __restrict__ hp_rows, const int* __restrict__ hp_cols,
    const float* __restrict__ hp_vals,
    int* __restrict__ bcursor,       // [NSB], zeroed
    uint2* __restrict__ bins,        // [NSB][BCAP]
    int* __restrict__ ofcnt,
    uint2* __restrict__ ofl,
    int n) {
  __shared__ float zs[GNODES][LDP];  // 33.8 KB
  __shared__ float wt[64][LDP];      // 33.8 KB (one j-half of W)

  int t = threadIdx.x;
  int bid = blockIdx.x;
  // Bresenham role split: exactly GGRID gemm blocks spread evenly.
  int g = (bid * GGRID) / TOTG;
  int gn = ((bid + 1) * GGRID) / TOTG;

  if (gn > g) {
    // ---------------- gemm block: nodes [g*64, g*64+64) ----------------
    int node0 = g * GNODES;
    int tn = t & 15;
    int tjg = t >> 4;   // 0..15
    int jb = tjg * 4;   // local j base within this half

    #pragma unroll
    for (int it = 0; it < 8; ++it) {
      int f = t + it * 256;
      int r = f >> 5;
      int c4 = f & 31;
      int node = node0 + r;
      float4 v = make_float4(0.f, 0.f, 0.f, 0.f);
      if (node < n) v = ((const float4*)(x + (size_t)node * D))[c4];
      *(float4*)&zs[r][c4 * 4] = v;
    }

    for (int jh = 0; jh < 2; ++jh) {
      if (jh) __syncthreads();  // half 0's wt readers done before overwrite
      #pragma unroll
      for (int it = 0; it < 8; ++it) {
        int f = t + it * 256;
        int j = f >> 5;
        int k4 = f & 31;
        *(float4*)&wt[j][k4 * 4] =
            ((const float4*)W)[(size_t)(jh * 64 + j) * 32 + k4];
      }
      __syncthreads();

      float acc[4][4] = {};
      #pragma unroll 2
      for (int k = 0; k < D; k += 4) {
        float4 w0 = *(const float4*)&wt[jb + 0][k];
        float4 w1 = *(const float4*)&wt[jb + 1][k];
        float4 w2 = *(const float4*)&wt[jb + 2][k];
        float4 w3 = *(const float4*)&wt[jb + 3][k];
        float4 z0 = *(const float4*)&zs[tn][k];
        float4 z1 = *(const float4*)&zs[tn + 16][k];
        float4 z2 = *(const float4*)&zs[tn + 32][k];
        float4 z3 = *(const float4*)&zs[tn + 48][k];
        acc[0][0] += z0.x*w0.x + z0.y*w0.y + z0.z*w0.z + z0.w*w0.w;
        acc[0][1] += z0.x*w1.x + z0.y*w1.y + z0.z*w1.z + z0.w*w1.w;
        acc[0][2] += z0.x*w2.x + z0.y*w2.y + z0.z*w2.z + z0.w*w2.w;
        acc[0][3] += z0.x*w3.x + z0.y*w3.y + z0.z*w3.z + z0.w*w3.w;
        acc[1][0] += z1.x*w0.x + z1.y*w0.y + z1.z*w0.z + z1.w*w0.w;
        acc[1][1] += z1.x*w1.x + z1.y*w1.y + z1.z*w1.z + z1.w*w1.w;
        acc[1][2] += z1.x*w2.x + z1.y*w2.y + z1.z*w2.z + z1.w*w2.w;
        acc[1][3] += z1.x*w3.x + z1.y*w3.y + z1.z*w3.z + z1.w*w3.w;
        acc[2][0] += z2.x*w0.x + z2.y*w0.y + z2.z*w0.z + z2.w*w0.w;
        acc[2][1] += z2.x*w1.x + z2.y*w1.y + z2.z*w1.z + z2.w*w1.w;
        acc[2][2] += z2.x*w2.x + z2.y*w2.y + z2.z*w2.z + z2.w*w2.w;
        acc[2][3] += z2.x*w3.x + z2.y*w3.y + z2.z*w3.z + z2.w*w3.w;
        acc[3][0] += z3.x*w0.x + z3.y*w0.y + z3.z*w0.z + z3.w*w0.w;
        acc[3][1] += z3.x*w1.x + z3.y*w1.y + z3.z*w1.z + z3.w*w1.w;
        acc[3][2] += z3.x*w2.x + z3.y*w2.y + z3.z*w2.z + z3.w*w2.w;
        acc[3][3] += z3.x*w3.x + z3.y*w3.y + z3.z*w3.z + z3.w*w3.w;
      }

      #pragma unroll
      for (int ii = 0; ii < 4; ++ii) {
        int node = node0 + ii * 16 + tn;
        if (node < n) {
          uint2 o;
          o.x = (unsigned)f2bf(acc[ii][0]) | ((unsigned)f2bf(acc[ii][1]) << 16);
          o.y = (unsigned)f2bf(acc[ii][2]) | ((unsigned)f2bf(acc[ii][3]) << 16);
          *(uint2*)&y[(size_t)node * 64 + jh * 32 + tjg * 2] = o;
        }
      }
    }
  } else {
    // ---------------- fill block: edges [fb*FEPB, fb*FEPB+FEPB) --------
    int fb = bid - g;
    int xcc = xcd_id();
    int e0 = fb * FEPB;
    int e1 = e0 + FEPB;
    if (e1 > N_EDGES2_C) e1 = N_EDGES2_C;
    for (int e = e0 + t; e < e1; e += 256) {
      int r, c;
      unsigned vb;
      if (e < N_EDGES_C) {
        r = __builtin_nontemporal_load(lp_rows + e);
        c = __builtin_nontemporal_load(lp_cols + e);
        vb = (__float_as_uint(__builtin_nontemporal_load(lp_vals + e)) & ~1u) | 1u;
      } else {
        int i = e - N_EDGES_C;
        r = __builtin_nontemporal_load(hp_rows + i);
        c = __builtin_nontemporal_load(hp_cols + i);
        vb = __float_as_uint(__builtin_nontemporal_load(hp_vals + i)) & ~1u;
      }
      int sb = xcc * NBKT + (r >> 2);
      int p = atomicAdd(&bcursor[sb], 1);
      if (p < BCAP) {
        bins[(size_t)sb * BCAP + p] =
            make_uint2(((unsigned)r << 16) | (unsigned)c, vb);
      } else {
        int q = atomicAdd(ofcnt, 1);
        if (q < OFCAP)
          ofl[q] = make_uint2(((unsigned)r << 16) | (unsigned)c, vb);
      }
    }
  }
}

// ---------------------------------------------------------------------------
// Kernel 3: gather — ONE WAVE PER BUCKET (4 rows). SPLIT lp/hp register
// accumulators per row (16 named regs); per-entry work is pure FMA into the
// set picked by the wave-uniform tag (flag<<2)|row via readfirstlane +
// 8-case scalar switch — NO per-entry alpha multiply. Alpha is computed in
// the EPILOGUE (4 dot-products vs L3-resident x, off the critical path):
// out = relu(a*lp + (1-a)*hp + bias); also writes the alpha output tail.
// 8 independent y-loads in flight. NO atomics, NO LDS, NO barriers.
// ---------------------------------------------------------------------------
__global__ __launch_bounds__(256) void gather_kernel(
    const int* __restrict__ bcursor,     // [NSHARD][NBKT]
    const uint2* __restrict__ bins,      // [NSB][BCAP]
    const unsigned* __restrict__ y,      // [N][64], word q = dims (2q,2q+1)
    const float* __restrict__ bias,
    const float* __restrict__ x,
    const float* __restrict__ aw,
    const float* __restrict__ ab,
    const int* __restrict__ ofcnt,
    const uint2* __restrict__ ofl,
    float* __restrict__ out,
    float* __restrict__ alpha_out) {
  int t = threadIdx.x;
  int w = t >> 6;
  int lane = t & 63;
  int bkt = blockIdx.x * 4 + w;   // 0..12499 (exact: 3125 blocks x 4 waves)

  // lp/hp accumulators for rows 0..3, dims (2*lane, 2*lane+1)
  float l0L = 0.f, l0H = 0.f, l1L = 0.f, l1H = 0.f;
  float l2L = 0.f, l2H = 0.f, l3L = 0.f, l3H = 0.f;
  float h0L = 0.f, h0H = 0.f, h1L = 0.f, h1H = 0.f;
  float h2L = 0.f, h2H = 0.f, h3L = 0.f, h3H = 0.f;

  // TAG = (flag<<2) | row :  0-3 = hp rows, 4-7 = lp rows
  #define ACC(TAG, VV, UU)                                       \
    do {                                                         \
      float uL_ = bf_lo(UU), uH_ = bf_hi(UU);                    \
      switch (TAG) {                                             \
        case 0: h0L += (VV) * uL_; h0H += (VV) * uH_; break;     \
        case 1: h1L += (VV) * uL_; h1H += (VV) * uH_; break;     \
        case 2: h2L += (VV) * uL_; h2H += (VV) * uH_; break;     \
        case 3: h3L += (VV) * uL_; h3H += (VV) * uH_; break;     \
        case 4: l0L += (VV) * uL_; l0H += (VV) * uH_; break;     \
        case 5: l1L += (VV) * uL_; l1H += (VV) * uH_; break;     \
        case 6: l2L += (VV) * uL_; l2H += (VV) * uH_; break;     \
        default: l3L += (VV) * uL_; l3H += (VV) * uH_; break;    \
      }                                                          \
    } while (0)
  #define TAG_OF(XK, VB) \
    ((int)__builtin_amdgcn_readfirstlane((((VB) & 1u) << 2) | (((XK) >> 16) & 3)))

  int cnts[8];
  uint2 wvs[8];
  #pragma unroll
  for (int s = 0; s < 8; ++s) {
    int c = bcursor[s * NBKT + bkt];
    cnts[s] = c > BCAP ? BCAP : c;
  }
  #pragma unroll
  for (int s = 0; s < 8; ++s) {
    wvs[s] = make_uint2(0u, 0u);
    if (lane < cnts[s])
      wvs[s] = bins[(size_t)(s * NBKT + bkt) * BCAP + lane];
  }

  #pragma unroll
  for (int s = 0; s < 8; ++s) {
    int cnt = cnts[s];
    uint2 wv = wvs[s];
    int i = 0;
    for (; i + 7 < cnt; i += 8) {   // 8 independent y-loads in flight
      unsigned xk0 = (unsigned)__shfl((int)wv.x, i + 0);
      unsigned xk1 = (unsigned)__shfl((int)wv.x, i + 1);
      unsigned xk2 = (unsigned)__shfl((int)wv.x, i + 2);
      unsigned xk3 = (unsigned)__shfl((int)wv.x, i + 3);
      unsigned xk4 = (unsigned)__shfl((int)wv.x, i + 4);
      unsigned xk5 = (unsigned)__shfl((int)wv.x, i + 5);
      unsigned xk6 = (unsigned)__shfl((int)wv.x, i + 6);
      unsigned xk7 = (unsigned)__shfl((int)wv.x, i + 7);
      unsigned vb0 = (unsigned)__shfl((int)wv.y, i + 0);
      unsigned vb1 = (unsigned)__shfl((int)wv.y, i + 1);
      unsigned vb2 = (unsigned)__shfl((int)wv.y, i + 2);
      unsigned vb3 = (unsigned)__shfl((int)wv.y, i + 3);
      unsigned vb4 = (unsigned)__shfl((int)wv.y, i + 4);
      unsigned vb5 = (unsigned)__shfl((int)wv.y, i + 5);
      unsigned vb6 = (unsigned)__shfl((int)wv.y, i + 6);
      unsigned vb7 = (unsigned)__shfl((int)wv.y, i + 7);
      unsigned u0 = y[(size_t)(xk0 & 0xffffu) * 64 + lane];
      unsigned u1 = y[(size_t)(xk1 & 0xffffu) * 64 + lane];
      unsigned u2 = y[(size_t)(xk2 & 0xffffu) * 64 + lane];
      unsigned u3 = y[(size_t)(xk3 & 0xffffu) * 64 + lane];
      unsigned u4 = y[(size_t)(xk4 & 0xffffu) * 64 + lane];
      unsigned u5 = y[(size_t)(xk5 & 0xffffu) * 64 + lane];
      unsigned u6 = y[(size_t)(xk6 & 0xffffu) * 64 + lane];
      unsigned u7 = y[(size_t)(xk7 & 0xffffu) * 64 + lane];
      ACC(TAG_OF(xk0, vb0), __uint_as_float(vb0 & ~1u), u0);
      ACC(TAG_OF(xk1, vb1), __uint_as_float(vb1 & ~1u), u1);
      ACC(TAG_OF(xk2, vb2), __uint_as_float(vb2 & ~1u), u2);
      ACC(TAG_OF(xk3, vb3), __uint_as_float(vb3 & ~1u), u3);
      ACC(TAG_OF(xk4, vb4), __uint_as_float(vb4 & ~1u), u4);
      ACC(TAG_OF(xk5, vb5), __uint_as_float(vb5 & ~1u), u5);
      ACC(TAG_OF(xk6, vb6), __uint_as_float(vb6 & ~1u), u6);
      ACC(TAG_OF(xk7, vb7), __uint_as_float(vb7 & ~1u), u7);
    }
    for (; i + 3 < cnt; i += 4) {   // quad tail
      unsigned xk0 = (unsigned)__shfl((int)wv.x, i + 0);
      unsigned xk1 = (unsigned)__shfl((int)wv.x, i + 1);
      unsigned xk2 = (unsigned)__shfl((int)wv.x, i + 2);
      unsigned xk3 = (unsigned)__shfl((int)wv.x, i + 3);
      unsigned vb0 = (unsigned)__shfl((int)wv.y, i + 0);
      unsigned vb1 = (unsigned)__shfl((int)wv.y, i + 1);
      unsigned vb2 = (unsigned)__shfl((int)wv.y, i + 2);
      unsigned vb3 = (unsigned)__shfl((int)wv.y, i + 3);
      unsigned u0 = y[(size_t)(xk0 & 0xffffu) * 64 + lane];
      unsigned u1 = y[(size_t)(xk1 & 0xffffu) * 64 + lane];
      unsigned u2 = y[(size_t)(xk2 & 0xffffu) * 64 + lane];
      unsigned u3 = y[(size_t)(xk3 & 0xffffu) * 64 + lane];
      ACC(TAG_OF(xk0, vb0), __uint_as_float(vb0 & ~1u), u0);
      ACC(TAG_OF(xk1, vb1), __uint_as_float(vb1 & ~1u), u1);
      ACC(TAG_OF(xk2, vb2), __uint_as_float(vb2 & ~1u), u2);
      ACC(TAG_OF(xk3, vb3), __uint_as_float(vb3 & ~1u), u3);
    }
    for (; i < cnt; ++i) {          // singles tail (<=3)
      unsigned xk0 = (unsigned)__shfl((int)wv.x, i);
      unsigned vb0 = (unsigned)__shfl((int)wv.y, i);
      unsigned u0 = y[(size_t)(xk0 & 0xffffu) * 64 + lane];
      ACC(TAG_OF(xk0, vb0), __uint_as_float(vb0 & ~1u), u0);
    }
  }

  // overflow entries (expected ~0-10 total): every wave scans, matches own bucket
  int nof = *ofcnt;
  if (nof > OFCAP) nof = OFCAP;
  for (int i = 0; i < nof; ++i) {
    uint2 o = ofl[i];
    unsigned r = o.x >> 16;
    if ((int)(r >> 2) == bkt) {
      unsigned u = y[(size_t)(o.x & 0xffffu) * 64 + lane];
      ACC((int)(((o.y & 1u) << 2) | (r & 3)), __uint_as_float(o.y & ~1u), u);
    }
  }
  #undef ACC
  #undef TAG_OF

  // ---- epilogue: alpha for the 4 rows (L3-hot x), then mix+bias+relu ----
  float awL = aw[lane], awH = aw[lane + 64];
  float bb = ab[0];
  const float* xr = x + (size_t)bkt * 4 * D;
  float s0 = xr[0 * D + lane] * awL + xr[0 * D + lane + 64] * awH;
  float s1 = xr[1 * D + lane] * awL + xr[1 * D + lane + 64] * awH;
  float s2 = xr[2 * D + lane] * awL + xr[2 * D + lane + 64] * awH;
  float s3 = xr[3 * D + lane] * awL + xr[3 * D + lane + 64] * awH;
  #pragma unroll
  for (int off = 32; off > 0; off >>= 1) {
    s0 += __shfl_down(s0, off);
    s1 += __shfl_down(s1, off);
    s2 += __shfl_down(s2, off);
    s3 += __shfl_down(s3, off);
  }
  float a0 = 1.0f / (1.0f + __expf(-(__shfl(s0, 0) + bb)));
  float a1 = 1.0f / (1.0f + __expf(-(__shfl(s1, 0) + bb)));
  float a2 = 1.0f / (1.0f + __expf(-(__shfl(s2, 0) + bb)));
  float a3 = 1.0f / (1.0f + __expf(-(__shfl(s3, 0) + bb)));
  if (lane == 0)
    *(float4*)&alpha_out[(size_t)bkt * 4] = make_float4(a0, a1, a2, a3);

  float2 bv = *(const float2*)&bias[lane * 2];
  size_t ro = (size_t)bkt * 4 * D + lane * 2;
  float2 o0, o1, o2, o3;
  o0.x = fmaxf(a0 * l0L + (1.f - a0) * h0L + bv.x, 0.0f);
  o0.y = fmaxf(a0 * l0H + (1.f - a0) * h0H + bv.y, 0.0f);
  o1.x = fmaxf(a1 * l1L + (1.f - a1) * h1L + bv.x, 0.0f);
  o1.y = fmaxf(a1 * l1H + (1.f - a1) * h1H + bv.y, 0.0f);
  o2.x = fmaxf(a2 * l2L + (1.f - a2) * h2L + bv.x, 0.0f);
  o2.y = fmaxf(a2 * l2H + (1.f - a2) * h2H + bv.y, 0.0f);
  o3.x = fmaxf(a3 * l3L + (1.f - a3) * h3L + bv.x, 0.0f);
  o3.y = fmaxf(a3 * l3H + (1.f - a3) * h3H + bv.y, 0.0f);
  *(float2*)&out[ro + 0 * D] = o0;
  *(float2*)&out[ro + 1 * D] = o1;
  *(float2*)&out[ro + 2 * D] = o2;
  *(float2*)&out[ro + 3 * D] = o3;
}

extern "C" void kernel_launch(void* const* d_in, const int* in_sizes, int n_in,
                              void* d_out, int out_size, void* d_ws, size_t ws_size,
                              hipStream_t stream) {
  const float* x = (const float*)d_in[0];
  const int* lp_rows = (const int*)d_in[1];
  const int* lp_cols = (const int*)d_in[2];
  const float* lp_vals = (const float*)d_in[3];
  const int* hp_rows = (const int*)d_in[4];
  const int* hp_cols = (const int*)d_in[5];
  const float* hp_vals = (const float*)d_in[6];
  const float* alpha_w = (const float*)d_in[7];
  const float* alpha_b = (const float*)d_in[8];
  const float* W = (const float*)d_in[9];
  const float* bias = (const float*)d_in[10];

  float* out = (float*)d_out;                      // [N, 128]
  float* alpha_out = out + (size_t)N_NODES_C * D;  // [N, 1] output tail

  char* ws = (char*)d_ws;
  unsigned* y = (unsigned*)ws;   ws += (size_t)N_NODES_C * 64 * 4;          // 12.8 MB
  float* alpha_ws = (float*)ws;  ws += 200192;                              // (unused, layout kept)
  int* bcursor = (int*)ws;       ws += (size_t)NSB * 4;                     // 400 KB
  int* ofcnt = (int*)ws;         ws += 256;                                 // adjacent to bcursor
  uint2* ofl = (uint2*)ws;       ws += (size_t)OFCAP * 8;                   // 32 KB
  uint2* bins = (uint2*)ws;
  ws += (size_t)NSB * BCAP * 8;                                            // 25.6 MB
  (void)alpha_ws;

  // Dispatch 1: zero cursors+ofcnt (int4, ~3 us)
  zero_kernel<<<((NSB + 64) / 4 + 255) / 256, 256, 0, stream>>>(
      (int4*)bcursor);

  // Dispatch 2: block-specialized gemm || fill (alpha-free, flag-in-LSB)
  gemm_fill_kernel<<<TOTG, 256, 0, stream>>>(
      x, W, y,
      lp_rows, lp_cols, lp_vals, hp_rows, hp_cols, hp_vals,
      bcursor, bins, ofcnt, ofl, N_NODES_C);

  // Dispatch 3: gather with split lp/hp accumulators + alpha epilogue
  gather_kernel<<<NBKT / 4, 256, 0, stream>>>(
      bcursor, bins, (const unsigned*)y, bias, x, alpha_w, alpha_b,
      ofcnt, ofl, out, alpha_out);
}

// Round 12
// 266.445 us; speedup vs baseline: 1.2109x; 1.2109x over previous
//
#include <hip/hip_runtime.h>

#define N_NODES_C 50000
#define N_EDGES_C 800000
#define N_EDGES2_C (2 * N_EDGES_C)
#define D 128
#define NSHARD 8
#define OFCAP 4096 // overflow list capacity (expected use ~3 edges)

// Bucketed append: BROWS rows per bucket, per-XCD sub-buckets.
#define BROWS 4
#define NBKT (N_NODES_C / BROWS)   // 12500 (exact)
#define NSB (NSHARD * NBKT)        // 100000 sub-buckets
#define BCAP 32                    // entries per sub-bucket (mean 16, +4 sigma)

#define GNODES 64
#define LDP 132                                            // pad: multiple of 4 floats
#define GGRID ((N_NODES_C + GNODES - 1) / GNODES)          // 782 gemm blocks
#define FGRID 2048                                         // fill blocks
#define FEPB ((N_EDGES2_C + FGRID - 1) / FGRID)            // 782 edges/block
#define TOTG (GGRID + FGRID)                               // 2830

static __device__ __forceinline__ unsigned short f2bf(float f) {
  unsigned u = __float_as_uint(f);
  u += 0x7fff + ((u >> 16) & 1);  // round-to-nearest-even
  return (unsigned short)(u >> 16);
}
static __device__ __forceinline__ float bf_lo(unsigned u) {
  return __uint_as_float(u << 16);
}
static __device__ __forceinline__ float bf_hi(unsigned u) {
  return __uint_as_float(u & 0xffff0000u);
}

// Physical XCD id (0..7), wave-uniform; steers L2 locality of the shards.
static __device__ __forceinline__ int xcd_id() {
  int v;
  asm volatile("s_getreg_b32 %0, hwreg(HW_REG_XCC_ID, 0, 4)" : "=s"(v));
  return v & (NSHARD - 1);
}

// ---------------------------------------------------------------------------
// Kernel 1: alpha[i] = sigmoid(dot(x[i], alpha_w) + alpha_b), wave per node,
// PLUS zeroing of bcursor[NSB] and ofcnt (adjacent in ws). (R6/R9 verified.)
// ---------------------------------------------------------------------------
__global__ __launch_bounds__(256) void alpha_zero_kernel(
    const float* __restrict__ x,
    const float* __restrict__ aw,
    const float* __restrict__ ab,
    float* __restrict__ alpha_out,
    float* __restrict__ alpha_ws,
    int* __restrict__ bcursor,   // zeroes [0, NSB + 64) ints (incl ofcnt)
    int n) {
  int gtid = blockIdx.x * blockDim.x + threadIdx.x;
  if (gtid < NSB + 64) bcursor[gtid] = 0;

  int wave = gtid >> 6;
  int lane = threadIdx.x & 63;
  if (wave >= n) return;
  const float* xr = x + (size_t)wave * D;
  float s = xr[lane] * aw[lane] + xr[lane + 64] * aw[lane + 64];
  #pragma unroll
  for (int off = 32; off > 0; off >>= 1)
    s += __shfl_down(s, off);
  if (lane == 0) {
    float a = 1.0f / (1.0f + __expf(-(s + ab[0])));
    alpha_out[wave] = a;
    alpha_ws[wave] = a;
  }
}

// ---------------------------------------------------------------------------
// Kernel 2 (FUSED, block-specialized): GGRID gemm blocks + FGRID fill blocks,
// Bresenham-interleaved. (R6/R9 verified body, unchanged.)
// ---------------------------------------------------------------------------
__global__ __launch_bounds__(256) void gemm_fill_kernel(
    const float* __restrict__ x,
    const float* __restrict__ W,
    unsigned* __restrict__ y,        // [N][64] packed words
    const int* __restrict__ lp_rows, const int* __restrict__ lp_cols,
    const float* __restrict__ lp_vals,
    const int* __restrict__ hp_rows, const int* __restrict__ hp_cols,
    const float* __restrict__ hp_vals,
    const float* __restrict__ alpha,
    int* __restrict__ bcursor,       // [NSB], zeroed
    uint2* __restrict__ bins,        // [NSB][BCAP]
    int* __restrict__ ofcnt,
    uint2* __restrict__ ofl,
    int n) {
  __shared__ float zs[GNODES][LDP];  // 33.8 KB
  __shared__ float wt[64][LDP];      // 33.8 KB (one j-half of W)

  int t = threadIdx.x;
  int bid = blockIdx.x;
  // Bresenham role split: exactly GGRID gemm blocks spread evenly.
  int g = (bid * GGRID) / TOTG;
  int gn = ((bid + 1) * GGRID) / TOTG;

  if (gn > g) {
    // ---------------- gemm block: nodes [g*64, g*64+64) ----------------
    int node0 = g * GNODES;
    int tn = t & 15;
    int tjg = t >> 4;   // 0..15
    int jb = tjg * 4;   // local j base within this half

    #pragma unroll
    for (int it = 0; it < 8; ++it) {
      int f = t + it * 256;
      int r = f >> 5;
      int c4 = f & 31;
      int node = node0 + r;
      float4 v = make_float4(0.f, 0.f, 0.f, 0.f);
      if (node < n) v = ((const float4*)(x + (size_t)node * D))[c4];
      *(float4*)&zs[r][c4 * 4] = v;
    }

    for (int jh = 0; jh < 2; ++jh) {
      if (jh) __syncthreads();  // half 0's wt readers done before overwrite
      #pragma unroll
      for (int it = 0; it < 8; ++it) {
        int f = t + it * 256;
        int j = f >> 5;
        int k4 = f & 31;
        *(float4*)&wt[j][k4 * 4] =
            ((const float4*)W)[(size_t)(jh * 64 + j) * 32 + k4];
      }
      __syncthreads();

      float acc[4][4] = {};
      #pragma unroll 2
      for (int k = 0; k < D; k += 4) {
        float4 w0 = *(const float4*)&wt[jb + 0][k];
        float4 w1 = *(const float4*)&wt[jb + 1][k];
        float4 w2 = *(const float4*)&wt[jb + 2][k];
        float4 w3 = *(const float4*)&wt[jb + 3][k];
        float4 z0 = *(const float4*)&zs[tn][k];
        float4 z1 = *(const float4*)&zs[tn + 16][k];
        float4 z2 = *(const float4*)&zs[tn + 32][k];
        float4 z3 = *(const float4*)&zs[tn + 48][k];
        acc[0][0] += z0.x*w0.x + z0.y*w0.y + z0.z*w0.z + z0.w*w0.w;
        acc[0][1] += z0.x*w1.x + z0.y*w1.y + z0.z*w1.z + z0.w*w1.w;
        acc[0][2] += z0.x*w2.x + z0.y*w2.y + z0.z*w2.z + z0.w*w2.w;
        acc[0][3] += z0.x*w3.x + z0.y*w3.y + z0.z*w3.z + z0.w*w3.w;
        acc[1][0] += z1.x*w0.x + z1.y*w0.y + z1.z*w0.z + z1.w*w0.w;
        acc[1][1] += z1.x*w1.x + z1.y*w1.y + z1.z*w1.z + z1.w*w1.w;
        acc[1][2] += z1.x*w2.x + z1.y*w2.y + z1.z*w2.z + z1.w*w2.w;
        acc[1][3] += z1.x*w3.x + z1.y*w3.y + z1.z*w3.z + z1.w*w3.w;
        acc[2][0] += z2.x*w0.x + z2.y*w0.y + z2.z*w0.z + z2.w*w0.w;
        acc[2][1] += z2.x*w1.x + z2.y*w1.y + z2.z*w1.z + z2.w*w1.w;
        acc[2][2] += z2.x*w2.x + z2.y*w2.y + z2.z*w2.z + z2.w*w2.w;
        acc[2][3] += z2.x*w3.x + z2.y*w3.y + z2.z*w3.z + z2.w*w3.w;
        acc[3][0] += z3.x*w0.x + z3.y*w0.y + z3.z*w0.z + z3.w*w0.w;
        acc[3][1] += z3.x*w1.x + z3.y*w1.y + z3.z*w1.z + z3.w*w1.w;
        acc[3][2] += z3.x*w2.x + z3.y*w2.y + z3.z*w2.z + z3.w*w2.w;
        acc[3][3] += z3.x*w3.x + z3.y*w3.y + z3.z*w3.z + z3.w*w3.w;
      }

      #pragma unroll
      for (int ii = 0; ii < 4; ++ii) {
        int node = node0 + ii * 16 + tn;
        if (node < n) {
          uint2 o;
          o.x = (unsigned)f2bf(acc[ii][0]) | ((unsigned)f2bf(acc[ii][1]) << 16);
          o.y = (unsigned)f2bf(acc[ii][2]) | ((unsigned)f2bf(acc[ii][3]) << 16);
          *(uint2*)&y[(size_t)node * 64 + jh * 32 + tjg * 2] = o;
        }
      }
    }
  } else {
    // ---------------- fill block: edges [fb*FEPB, fb*FEPB+FEPB) --------
    int fb = bid - g;
    int xcc = xcd_id();
    int e0 = fb * FEPB;
    int e1 = e0 + FEPB;
    if (e1 > N_EDGES2_C) e1 = N_EDGES2_C;
    for (int e = e0 + t; e < e1; e += 256) {
      int r, c;
      float v;
      if (e < N_EDGES_C) {
        r = __builtin_nontemporal_load(lp_rows + e);
        c = __builtin_nontemporal_load(lp_cols + e);
        v = __builtin_nontemporal_load(lp_vals + e) * alpha[r];
      } else {
        int i = e - N_EDGES_C;
        r = __builtin_nontemporal_load(hp_rows + i);
        c = __builtin_nontemporal_load(hp_cols + i);
        v = __builtin_nontemporal_load(hp_vals + i) * (1.0f - alpha[r]);
      }
      int sb = xcc * NBKT + (r >> 2);
      int p = atomicAdd(&bcursor[sb], 1);
      if (p < BCAP) {
        bins[(size_t)sb * BCAP + p] =
            make_uint2(((unsigned)r << 16) | (unsigned)c, __float_as_uint(v));
      } else {
        int q = atomicAdd(ofcnt, 1);
        if (q < OFCAP)
          ofl[q] = make_uint2(((unsigned)r << 16) | (unsigned)c,
                              (unsigned)__float_as_int(v));
      }
    }
  }
}

// ---------------------------------------------------------------------------
// Kernel 3: gather — ONE WAVE PER BUCKET (4 rows), register accumulation.
// CHANGE vs R9 (single variable): the per-entry __shfl broadcasts (2x
// ds_bpermute through the LDS pipe, 6.4M total) are replaced with
// __builtin_amdgcn_readlane at COMPILE-TIME slot indices (unrolled 4-entry
// batches, wave-uniform `cnt<=b` early-out). readlane results live in SGPRs:
// row tag decodes in SALU (free pipe), y-address is scalar-base + lane*4
// (saddr form), value feeds v_fmac as the one allowed scalar operand.
// Zero-padded slots contribute exactly 0.0 — no per-entry guards. R11's
// counters showed gather is decode/VALU-bound (VALUBusy 55%), not memory-
// bound; this cuts per-entry VALU ~2.5x. NO atomics, NO LDS, NO barriers.
// ---------------------------------------------------------------------------
__global__ __launch_bounds__(256) void gather_kernel(
    const int* __restrict__ bcursor,     // [NSHARD][NBKT]
    const uint2* __restrict__ bins,      // [NSB][BCAP]
    const unsigned* __restrict__ y,      // [N][64], word q = dims (2q,2q+1)
    const float* __restrict__ bias,
    const int* __restrict__ ofcnt,
    const uint2* __restrict__ ofl,
    float* __restrict__ out) {
  int t = threadIdx.x;
  int w = t >> 6;
  int lane = t & 63;
  int bkt = blockIdx.x * 4 + w;   // 0..12499 (exact: 3125 blocks x 4 waves)

  float a0L = 0.f, a0H = 0.f, a1L = 0.f, a1H = 0.f;
  float a2L = 0.f, a2H = 0.f, a3L = 0.f, a3H = 0.f;

  #define ACC(RR, VV, UU)                                        \
    do {                                                         \
      float uL_ = bf_lo(UU), uH_ = bf_hi(UU);                    \
      switch (RR) {                                              \
        case 0: a0L += (VV) * uL_; a0H += (VV) * uH_; break;     \
        case 1: a1L += (VV) * uL_; a1H += (VV) * uH_; break;     \
        case 2: a2L += (VV) * uL_; a2H += (VV) * uH_; break;     \
        default: a3L += (VV) * uL_; a3H += (VV) * uH_; break;    \
      }                                                          \
    } while (0)

  int cnts[8];
  uint2 wvs[8];
  #pragma unroll
  for (int s = 0; s < 8; ++s) {
    int c = bcursor[s * NBKT + bkt];
    cnts[s] = c > BCAP ? BCAP : c;
  }
  #pragma unroll
  for (int s = 0; s < 8; ++s) {
    wvs[s] = make_uint2(0u, 0u);   // zero-pad: spurious slots add 0.0
    if (lane < cnts[s])
      wvs[s] = bins[(size_t)(s * NBKT + bkt) * BCAP + lane];
  }

  #pragma unroll
  for (int s = 0; s < 8; ++s) {
    int cnt = cnts[s];
    uint2 wv = wvs[s];
    #pragma unroll
    for (int b = 0; b < BCAP; b += 4) {
      if (cnt <= b) break;  // wave-uniform early-out per 4-entry batch
      unsigned xk0 = __builtin_amdgcn_readlane(wv.x, b + 0);
      unsigned xk1 = __builtin_amdgcn_readlane(wv.x, b + 1);
      unsigned xk2 = __builtin_amdgcn_readlane(wv.x, b + 2);
      unsigned xk3 = __builtin_amdgcn_readlane(wv.x, b + 3);
      unsigned vb0 = __builtin_amdgcn_readlane(wv.y, b + 0);
      unsigned vb1 = __builtin_amdgcn_readlane(wv.y, b + 1);
      unsigned vb2 = __builtin_amdgcn_readlane(wv.y, b + 2);
      unsigned vb3 = __builtin_amdgcn_readlane(wv.y, b + 3);
      unsigned u0 = y[(size_t)(xk0 & 0xffffu) * 64 + lane];
      unsigned u1 = y[(size_t)(xk1 & 0xffffu) * 64 + lane];
      unsigned u2 = y[(size_t)(xk2 & 0xffffu) * 64 + lane];
      unsigned u3 = y[(size_t)(xk3 & 0xffffu) * 64 + lane];
      ACC((int)((xk0 >> 16) & 3), __uint_as_float(vb0), u0);
      ACC((int)((xk1 >> 16) & 3), __uint_as_float(vb1), u1);
      ACC((int)((xk2 >> 16) & 3), __uint_as_float(vb2), u2);
      ACC((int)((xk3 >> 16) & 3), __uint_as_float(vb3), u3);
    }
  }

  // overflow entries (expected ~0-10 total): every wave scans, matches own bucket
  int nof = *ofcnt;
  if (nof > OFCAP) nof = OFCAP;
  for (int i = 0; i < nof; ++i) {
    uint2 o = ofl[i];
    unsigned r = o.x >> 16;
    if ((int)(r >> 2) == bkt) {
      unsigned u = y[(size_t)(o.x & 0xffffu) * 64 + lane];
      float v = __uint_as_float(o.y);
      ACC((int)(r & 3), v, u);
    }
  }
  #undef ACC

  float2 bv = *(const float2*)&bias[lane * 2];
  size_t ro = (size_t)bkt * 4 * D + lane * 2;
  float2 o0, o1, o2, o3;
  o0.x = fmaxf(a0L + bv.x, 0.0f); o0.y = fmaxf(a0H + bv.y, 0.0f);
  o1.x = fmaxf(a1L + bv.x, 0.0f); o1.y = fmaxf(a1H + bv.y, 0.0f);
  o2.x = fmaxf(a2L + bv.x, 0.0f); o2.y = fmaxf(a2H + bv.y, 0.0f);
  o3.x = fmaxf(a3L + bv.x, 0.0f); o3.y = fmaxf(a3H + bv.y, 0.0f);
  *(float2*)&out[ro + 0 * D] = o0;
  *(float2*)&out[ro + 1 * D] = o1;
  *(float2*)&out[ro + 2 * D] = o2;
  *(float2*)&out[ro + 3 * D] = o3;
}

extern "C" void kernel_launch(void* const* d_in, const int* in_sizes, int n_in,
                              void* d_out, int out_size, void* d_ws, size_t ws_size,
                              hipStream_t stream) {
  const float* x = (const float*)d_in[0];
  const int* lp_rows = (const int*)d_in[1];
  const int* lp_cols = (const int*)d_in[2];
  const float* lp_vals = (const float*)d_in[3];
  const int* hp_rows = (const int*)d_in[4];
  const int* hp_cols = (const int*)d_in[5];
  const float* hp_vals = (const float*)d_in[6];
  const float* alpha_w = (const float*)d_in[7];
  const float* alpha_b = (const float*)d_in[8];
  const float* W = (const float*)d_in[9];
  const float* bias = (const float*)d_in[10];

  float* out = (float*)d_out;                      // [N, 128]
  float* alpha_out = out + (size_t)N_NODES_C * D;  // [N, 1] output tail

  char* ws = (char*)d_ws;
  unsigned* y = (unsigned*)ws;   ws += (size_t)N_NODES_C * 64 * 4;          // 12.8 MB
  float* alpha_ws = (float*)ws;  ws += 200192;
  int* bcursor = (int*)ws;       ws += (size_t)NSB * 4;                     // 400 KB
  int* ofcnt = (int*)ws;         ws += 256;                                 // adjacent to bcursor
  uint2* ofl = (uint2*)ws;       ws += (size_t)OFCAP * 8;                   // 32 KB
  uint2* bins = (uint2*)ws;
  ws += (size_t)NSB * BCAP * 8;                                            // 25.6 MB

  // Dispatch 1: alpha + cursor/ofcnt zeroing
  alpha_zero_kernel<<<(N_NODES_C + 3) / 4, 256, 0, stream>>>(
      x, alpha_w, alpha_b, alpha_out, alpha_ws, bcursor, N_NODES_C);

  // Dispatch 2: block-specialized gemm || fill (bucketed append)
  gemm_fill_kernel<<<TOTG, 256, 0, stream>>>(
      x, W, y,
      lp_rows, lp_cols, lp_vals, hp_rows, hp_cols, hp_vals,
      alpha_ws, bcursor, bins, ofcnt, ofl, N_NODES_C);

  // Dispatch 3: bucket gather (wave per bucket, readlane decode)
  gather_kernel<<<NBKT / 4, 256, 0, stream>>>(
      bcursor, bins, (const unsigned*)y, bias, ofcnt, ofl, out);
}